// Round 4
// baseline (217.493 us; speedup 1.0000x reference)
//
#include <hip/hip_runtime.h>
#include <cstdint>

// Two-link planar arm forward dynamics: qdd = M(q)^-1 (tau - h(q,dq)).
// fp32 in / fp32 out. Purely elementwise -> memory-bound.
// Round-2 post-mortem: 83 us at 2.0 TB/s, VALUBusy 13%, occupancy 68% ->
// latency/MLP-bound, not BW-bound. Fix: persistent grid-stride kernel
// (2048 blocks = 8/CU), 2-deep software pipeline (6 outstanding 16B loads
// per wave instead of 3), nontemporal stores (output never re-read).
// Round-3: __builtin_nontemporal_store needs a NATIVE clang vector type,
// not HIP_vector_type — use ext_vector_type(4) float throughout.

#define BLOCK 256
#define GRID  2048   // 8 blocks/CU * 256 CU -> full 32 waves/CU occupancy

typedef float f4 __attribute__((ext_vector_type(4)));

__device__ __forceinline__ f4 fd_compute(f4 qv, f4 dv, f4 tv) {
    // Arm constants (L1=L2=1, C1=C2=0.5, M1=M2=1, I1=I2=0.1, G=9.81)
    const float alpha = 1.7f;     // I1 + M1*C1^2 + I2 + M2*(L1^2 + C2^2)
    const float beta  = 0.5f;     // M2*L1*C2
    const float delta = 0.35f;    // I2 + M2*C2^2  (== M22)
    const float G     = 9.81f;
    const float gA    = 1.5f * G; // (M1*C1 + M2*L1)*G
    const float gB    = 0.5f * G; // M2*C2*G

    f4 ov;

#pragma unroll
    for (int j = 0; j < 2; ++j) {
        float q1   = qv[2 * j + 0];
        float q2   = qv[2 * j + 1];
        float dq1  = dv[2 * j + 0];
        float dq2  = dv[2 * j + 1];
        float tau1 = tv[2 * j + 0];
        float tau2 = tv[2 * j + 1];

        float c2 = __cosf(q2);
        float s2 = __sinf(q2);

        float M11 = alpha + 2.0f * beta * c2;
        float M12 = delta + beta * c2;
        float M22 = delta;

        float cq1  = __cosf(q1);
        float cq12 = __cosf(q1 + q2);

        float g1 = gA * cq1 + gB * cq12;
        float g2 = gB * cq12;

        float h1 = -beta * s2 * (2.0f * dq1 * dq2 + dq2 * dq2) + g1;
        float h2 =  beta * s2 * dq1 * dq1 + g2;

        float r1 = tau1 - h1;
        float r2 = tau2 - h2;

        float det  = M11 * M22 - M12 * M12;
        float rdet = __builtin_amdgcn_rcpf(det);   // v_rcp_f32, ~1 ulp

        ov[2 * j + 0] = (M22 * r1 - M12 * r2) * rdet;
        ov[2 * j + 1] = (M11 * r2 - M12 * r1) * rdet;
    }
    return ov;
}

__global__ __launch_bounds__(BLOCK) void fd_qdd_kernel(
    const f4* __restrict__ qp,
    const f4* __restrict__ dqp,
    const f4* __restrict__ taup,
    f4* __restrict__ outp,
    int nvec)  // number of float4 groups (= 2 rows each)
{
    const int tid = blockIdx.x * BLOCK + threadIdx.x;
    const int nt  = GRID * BLOCK;          // total threads (grid-stride)
    const int nt2 = 2 * nt;

    // Main loop: 2 iterations pipelined — all 6 loads issued before computes.
    int idx = tid;
    for (; idx + nt < nvec; idx += nt2) {
        int i0 = idx, i1 = idx + nt;
        f4 q0 = qp[i0];
        f4 d0 = dqp[i0];
        f4 t0 = taup[i0];
        f4 q1 = qp[i1];
        f4 d1 = dqp[i1];
        f4 t1 = taup[i1];

        f4 o0 = fd_compute(q0, d0, t0);
        f4 o1 = fd_compute(q1, d1, t1);

        __builtin_nontemporal_store(o0, &outp[i0]);
        __builtin_nontemporal_store(o1, &outp[i1]);
    }
    // Tail (not taken for B = 8388608, but keep it general).
    if (idx < nvec) {
        f4 o = fd_compute(qp[idx], dqp[idx], taup[idx]);
        __builtin_nontemporal_store(o, &outp[idx]);
    }
}

extern "C" void kernel_launch(void* const* d_in, const int* in_sizes, int n_in,
                              void* d_out, int out_size, void* d_ws, size_t ws_size,
                              hipStream_t stream) {
    const f4* q   = (const f4*)d_in[0];
    const f4* dq  = (const f4*)d_in[1];
    const f4* tau = (const f4*)d_in[2];
    f4*       out = (f4*)d_out;

    int n_elems = in_sizes[0];      // B*2 fp32 elements
    int nvec    = n_elems / 4;      // 4 fp32 per float4 (2 rows)

    fd_qdd_kernel<<<GRID, BLOCK, 0, stream>>>(q, dq, tau, out, nvec);
}

// Round 5
// 197.143 us; speedup vs baseline: 1.1032x; 1.1032x over previous
//
#include <hip/hip_runtime.h>
#include <cstdint>

// Two-link planar arm forward dynamics: qdd = M(q)^-1 (tau - h(q,dq)).
// fp32 in / fp32 out. Purely elementwise -> memory-bound.
//
// Round-4 post-mortem: 87 us, ~2 TB/s HBM, VALUBusy 9.7%, occupancy 57%.
// Doubling per-wave MLP (3->6 outstanding loads) changed NOTHING vs round 2
// => limiter is a per-CU outstanding-miss cap (L1/TA miss tracking), not
// per-wave MLP. ~128 tracked lines x 64B ~= 8KB in flight/CU at ~900-2000cy
// latency = ~10 B/cyc/CU — matches measurement exactly.
//
// Round-5 experiment: nontemporal (streaming) LOADS to bypass L1 allocation
// — inputs are read exactly once, so L1/L2 allocation is pure overhead.
// Everything else identical to round 4 for a clean A/B.

#define BLOCK 256
#define GRID  2048   // 8 blocks/CU * 256 CU -> full 32 waves/CU occupancy

typedef float f4 __attribute__((ext_vector_type(4)));

__device__ __forceinline__ f4 fd_compute(f4 qv, f4 dv, f4 tv) {
    // Arm constants (L1=L2=1, C1=C2=0.5, M1=M2=1, I1=I2=0.1, G=9.81)
    const float alpha = 1.7f;     // I1 + M1*C1^2 + I2 + M2*(L1^2 + C2^2)
    const float beta  = 0.5f;     // M2*L1*C2
    const float delta = 0.35f;    // I2 + M2*C2^2  (== M22)
    const float G     = 9.81f;
    const float gA    = 1.5f * G; // (M1*C1 + M2*L1)*G
    const float gB    = 0.5f * G; // M2*C2*G

    f4 ov;

#pragma unroll
    for (int j = 0; j < 2; ++j) {
        float q1   = qv[2 * j + 0];
        float q2   = qv[2 * j + 1];
        float dq1  = dv[2 * j + 0];
        float dq2  = dv[2 * j + 1];
        float tau1 = tv[2 * j + 0];
        float tau2 = tv[2 * j + 1];

        float c2 = __cosf(q2);
        float s2 = __sinf(q2);

        float M11 = alpha + 2.0f * beta * c2;
        float M12 = delta + beta * c2;
        float M22 = delta;

        float cq1  = __cosf(q1);
        float cq12 = __cosf(q1 + q2);

        float g1 = gA * cq1 + gB * cq12;
        float g2 = gB * cq12;

        float h1 = -beta * s2 * (2.0f * dq1 * dq2 + dq2 * dq2) + g1;
        float h2 =  beta * s2 * dq1 * dq1 + g2;

        float r1 = tau1 - h1;
        float r2 = tau2 - h2;

        float det  = M11 * M22 - M12 * M12;
        float rdet = __builtin_amdgcn_rcpf(det);   // v_rcp_f32, ~1 ulp

        ov[2 * j + 0] = (M22 * r1 - M12 * r2) * rdet;
        ov[2 * j + 1] = (M11 * r2 - M12 * r1) * rdet;
    }
    return ov;
}

__global__ __launch_bounds__(BLOCK) void fd_qdd_kernel(
    const f4* __restrict__ qp,
    const f4* __restrict__ dqp,
    const f4* __restrict__ taup,
    f4* __restrict__ outp,
    int nvec)  // number of float4 groups (= 2 rows each)
{
    const int tid = blockIdx.x * BLOCK + threadIdx.x;
    const int nt  = GRID * BLOCK;          // total threads (grid-stride)
    const int nt2 = 2 * nt;

    // Main loop: 2 iterations pipelined — all 6 streaming loads issued
    // before either compute.
    int idx = tid;
    for (; idx + nt < nvec; idx += nt2) {
        int i0 = idx, i1 = idx + nt;
        f4 q0 = __builtin_nontemporal_load(&qp[i0]);
        f4 d0 = __builtin_nontemporal_load(&dqp[i0]);
        f4 t0 = __builtin_nontemporal_load(&taup[i0]);
        f4 q1 = __builtin_nontemporal_load(&qp[i1]);
        f4 d1 = __builtin_nontemporal_load(&dqp[i1]);
        f4 t1 = __builtin_nontemporal_load(&taup[i1]);

        f4 o0 = fd_compute(q0, d0, t0);
        f4 o1 = fd_compute(q1, d1, t1);

        __builtin_nontemporal_store(o0, &outp[i0]);
        __builtin_nontemporal_store(o1, &outp[i1]);
    }
    // Tail (not taken for B = 8388608, but keep it general).
    if (idx < nvec) {
        f4 q = __builtin_nontemporal_load(&qp[idx]);
        f4 d = __builtin_nontemporal_load(&dqp[idx]);
        f4 t = __builtin_nontemporal_load(&taup[idx]);
        f4 o = fd_compute(q, d, t);
        __builtin_nontemporal_store(o, &outp[idx]);
    }
}

extern "C" void kernel_launch(void* const* d_in, const int* in_sizes, int n_in,
                              void* d_out, int out_size, void* d_ws, size_t ws_size,
                              hipStream_t stream) {
    const f4* q   = (const f4*)d_in[0];
    const f4* dq  = (const f4*)d_in[1];
    const f4* tau = (const f4*)d_in[2];
    f4*       out = (f4*)d_out;

    int n_elems = in_sizes[0];      // B*2 fp32 elements
    int nvec    = n_elems / 4;      // 4 fp32 per float4 (2 rows)

    fd_qdd_kernel<<<GRID, BLOCK, 0, stream>>>(q, dq, tau, out, nvec);
}